// Round 4
// baseline (371.113 us; speedup 1.0000x reference)
//
#include <hip/hip_runtime.h>

// Problem constants
#define MDIM 8192
#define IDIM 1024
#define ODIM 1024
#define D1   9            // DEGREE+1
#define KDIM (IDIM * D1)  // 9216, k = d*1024 + i ordering

typedef _Float16 half8   __attribute__((ext_vector_type(8)));
typedef _Float16 half2v  __attribute__((ext_vector_type(2)));
typedef float    float4v __attribute__((ext_vector_type(4)));

#define BSCALE 256.0f     // pre-scale B into f16-normal range (exact pow2)
#define INV_BSCALE (1.0f / 256.0f)
#define USCALE 5.123105625617661f    // sqrt(17) + 1
#define H0C 0.7511255444649425f     // pi^-1/4
#define SQRT2 1.4142135623730951f   // h1 = sqrt2 * u * h0

// ---------------------------------------------------------------------------
// hermite9 (fp32) — naive fallback only.
// ---------------------------------------------------------------------------
__device__ __forceinline__ void hermite9(float xv, float h[D1]) {
    float ax = fabsf(xv);
    float t  = __expf(-2.0f * ax);
    float th = (1.0f - t) / (1.0f + t);
    th = copysignf(th, xv);
    float u = th * USCALE;
    float g = __expf(-0.5f * u * u);
    h[0] = H0C * g;
    h[1] = SQRT2 * H0C * u * g;
    const float c1[D1] = {0.f, 0.f, 1.0f, 0.8164965809277260f, 0.7071067811865476f,
                          0.6324555320336759f, 0.5773502691896258f, 0.5345224838248488f, 0.5f};
    const float c2[D1] = {0.f, 0.f, 0.7071067811865476f, 0.8164965809277260f, 0.8660254037844386f,
                          0.8944271909999159f, 0.9128709291752769f, 0.9258200997725514f, 0.9354143466934853f};
#pragma unroll
    for (int d = 2; d < D1; ++d) h[d] = c1[d] * u * h[d - 1] - c2[d] * h[d - 2];
}

// ---------------------------------------------------------------------------
// prep_all: fused prep_b (blocks 0..1023) + prep_u (blocks 1024..5119).
// The two phases are independent; fusing them overlaps their execution and
// removes one launch gap.
// ---------------------------------------------------------------------------
__global__ __launch_bounds__(256) void prep_all(const float* __restrict__ C,
                                                const float* __restrict__ x,
                                                _Float16* __restrict__ Bt,
                                                _Float16* __restrict__ U,
                                                _Float16* __restrict__ H0) {
    __shared__ float lds[288 * 33];
    const int t = threadIdx.x;
    if (blockIdx.x < 1024) {
        // ---- prep_b: LDS transpose, 32i x 32o tile, half8 stores ----------
        const int ti = blockIdx.x & 31;
        const int to = blockIdx.x >> 5;
        const float* base = C + (size_t)ti * 32 * 9216 + (size_t)to * 32 * 9;
#pragma unroll
        for (int j = 0; j < 36; ++j) {
            int f   = t + 256 * j;
            int row = f / 288;
            int col = f - row * 288;
            lds[col * 33 + row] = base[(size_t)row * 9216 + col];
        }
        __syncthreads();
        _Float16* bb = Bt + (size_t)to * 32 * KDIM + ti * 32;
#pragma unroll
        for (int j = 0; j < 5; ++j) {
            int s = t + 256 * j;
            if (s < 1152) {
                int i8  = s & 3;          // which half8 within the 32-i run
                int odp = s >> 2;         // 0..287 = o_local*9 + d
                int ol  = odp / 9;
                int d   = odp - ol * 9;
                half8 vv;
#pragma unroll
                for (int e = 0; e < 8; ++e)
                    vv[e] = (_Float16)(lds[odp * 33 + i8 * 8 + e] * BSCALE);
                *(half8*)(bb + (size_t)ol * KDIM + d * IDIM + i8 * 8) = vv;
            }
        }
    } else {
        // ---- prep_u: x -> u = USCALE*tanh(x), h0 = pi^-1/4 exp(-u^2/2) ----
        size_t tt = (size_t)(blockIdx.x - 1024) * 256 + t;
        const float4* xp = (const float4*)(x + tt * 8);
        float4 a0 = xp[0], a1 = xp[1];
        float xv[8] = {a0.x, a0.y, a0.z, a0.w, a1.x, a1.y, a1.z, a1.w};
        half8 uu, hh;
#pragma unroll
        for (int e = 0; e < 8; ++e) {
            float v  = xv[e];
            float t2 = __expf(-2.0f * fabsf(v));
            float th = (1.0f - t2) / (1.0f + t2);
            float u  = copysignf(th, v) * USCALE;
            float g  = __expf(-0.5f * u * u);
            uu[e] = (_Float16)u;
            hh[e] = (_Float16)(H0C * g);
        }
        *(half8*)(U  + tt * 8) = uu;
        *(half8*)(H0 + tt * 8) = hh;
    }
}

// ---------------------------------------------------------------------------
// gemm_fused5: occupancy fix. Tile 128x64 (grid 16x64 = 1024 blocks = 4/CU,
// was 512 = 2/CU grid-capped). Wave shape stays 64 rows x 32 cols (2x2 wave
// grid) so B ds_read traffic per FLOP is UNCHANGED and A-state stays 8 slots.
// acc shrinks 64->32 VGPR, Bs shrinks to 3 x 8 KB = 24 KB -> occupancy now
// min(grid 4, LDS 6, VGPR ~5) = 4 blocks/CU = 4 waves/SIMD (was 2).
// A-operand in registers (Hermite recurrence pointwise in MFMA A-fragment
// layout); Bs triple-buffered, DMA 2 windows ahead, steady s_waitcnt vmcnt(2)
// (never 0 in main loop); UH prefetch at d==8 into then-dead u8/hA8 regs.
// ---------------------------------------------------------------------------
__global__ __launch_bounds__(256, 3) void gemm_fused5(
    const _Float16* __restrict__ U,    // [8192][1024] f16
    const _Float16* __restrict__ H0,   // [8192][1024] f16
    const _Float16* __restrict__ Bt,   // [ODIM][KDIM], pre-scaled by 256
    float* __restrict__ out)           // [8192][ODIM]
{
    const int tid = threadIdx.x;
    const int w = tid >> 6;
    const int l = tid & 63;
    const int bn = blockIdx.x;    // n-tile 0..15 (64 cols each)
    const int bm = blockIdx.y;    // m-tile 0..63 (128 rows each)

    __shared__ _Float16 Bs[3][64 * 64];      // 24 KB, triple buffer

    // Bs staging: lane l, rep rr loads 16B; stored kgrp = (l&7)^(l>>3)
    const int lrow8 = l >> 3;
    const int kgrp  = (l & 7) ^ lrow8;
    const _Float16* Bg = Bt + ((size_t)(bn * 64 + w * 8 + lrow8) * KDIM + kgrp * 8);

    // compute-side fragment indices
    const int q   = l >> 4;
    const int m16 = l & 15;
    const int s3  = m16 & 7;
    const int wm  = w >> 1, wn = w & 1;   // 2x2 wave grid: 64 rows x 32 cols

    // per-lane A-state: rows bm*128 + wm*64 + i16*16 + m16 (i16=0..3),
    // i-groups g = q + 4*ko (ko=0..1): 8 half8 slots, s = i16*2 + ko
    const size_t ubase = ((size_t)(bm * 128 + wm * 64 + m16)) << 10;

    constexpr float c1a[D1] = {0.f, 0.f, 1.0f, 0.8164965809277260f, 0.7071067811865476f,
                               0.6324555320336759f, 0.5773502691896258f, 0.5345224838248488f, 0.5f};
    constexpr float c2a[D1] = {0.f, 0.f, 0.7071067811865476f, 0.8164965809277260f, 0.8660254037844386f,
                               0.8944271909999159f, 0.9128709291752769f, 0.9258200997725514f, 0.9354143466934853f};

    half8 u8[8], hA8[8], hB8[8];

    // load u and h0 for i-block ib into u8 / hA8 (hA8 <- h0)
    auto loadUH = [&](int ib) {
        const int ibo = ib * 64;
#pragma unroll
        for (int i16 = 0; i16 < 4; ++i16)
#pragma unroll
            for (int ko = 0; ko < 2; ++ko) {
                const size_t off = ubase + ((size_t)(i16 * 16) << 10) + ibo + (q + 4 * ko) * 8;
                u8 [i16 * 2 + ko] = *(const half8*)(U  + off);
                hA8[i16 * 2 + ko] = *(const half8*)(H0 + off);
            }
    };

    // DMA one 64x64 B-tile (k-offset nkoff) into Bs[nbuf] (2 instrs/wave)
    auto dmaB = [&](int nkoff, int nbuf) {
#pragma unroll
        for (int rr = 0; rr < 2; ++rr)
            __builtin_amdgcn_global_load_lds(
                (const __attribute__((address_space(1))) void*)(Bg + (size_t)(rr * 32) * KDIM + nkoff),
                (__attribute__((address_space(3))) void*)((char*)&Bs[nbuf][0] + (rr * 4 + w) * 1024),
                16, 0, 0);
    };

    float4v acc[4][2] = {};

    // ---- prologue ---------------------------------------------------------
    loadUH(0);                 // 16 loads (oldest in FIFO)
    dmaB(0, 0);                // batch(0)
    dmaB(IDIM, 1);             // batch(1)
    // retire UH + batch(0); batch(1) stays in flight
    asm volatile("s_waitcnt vmcnt(2)" ::: "memory");
    __builtin_amdgcn_s_barrier();
    asm volatile("" ::: "memory");

    // ---- one window (t = ib*9 + d); d is compile-time within unroll -------
    auto window = [&](int ib, int d, bool do_uh, bool do_dma, int waitN, bool do_sync) {
        const int cbuf = d % 3;

        // (A) i-block UH prefetch: u8/hA8 are dead at d==8 (af uses hB8 only)
        if (do_uh) loadUH(ib + 1);

        // (B) MFMA on Bs[cbuf] with A-frags straight from registers
        __builtin_amdgcn_s_setprio(1);
#pragma unroll
        for (int ko = 0; ko < 2; ++ko) {
            const int slot = (q + 4 * ko) ^ s3;
            half8 bf[2];
#pragma unroll
            for (int j = 0; j < 2; ++j)
                bf[j] = *(const half8*)&Bs[cbuf][(wn * 32 + j * 16 + m16) * 64 + slot * 8];
#pragma unroll
            for (int i = 0; i < 4; ++i) {
                half8 af = (d == 0) ? hA8[i * 2 + ko] : hB8[i * 2 + ko];
#pragma unroll
                for (int j = 0; j < 2; ++j)
                    acc[i][j] = __builtin_amdgcn_mfma_f32_16x16x32_f16(af, bf[j], acc[i][j], 0, 0, 0);
            }
        }
        __builtin_amdgcn_s_setprio(0);

        // (C) recurrence: advance state to degree d+1 (skip at d==8)
        if (d == 0) {
            const _Float16 s2 = (_Float16)SQRT2;
            half8 s2v = {s2, s2, s2, s2, s2, s2, s2, s2};
#pragma unroll
            for (int p = 0; p < 8; ++p) hB8[p] = s2v * u8[p] * hA8[p];   // h1; hA8 keeps h0
        } else if (d <= 7) {
            const _Float16 c1 = (_Float16)c1a[d + 1];
            const _Float16 c2 = (_Float16)c2a[d + 1];
            half8 c1v = {c1, c1, c1, c1, c1, c1, c1, c1};
            half8 c2v = {c2, c2, c2, c2, c2, c2, c2, c2};
#pragma unroll
            for (int p = 0; p < 8; ++p) {
                half8 tt = u8[p] * hB8[p];
                half8 ht = c1v * tt - c2v * hA8[p];
                hA8[p] = hB8[p];
                hB8[p] = ht;
            }
        }

        // (D) DMA batch(t+2) -> Bs[(t+2)%3]
        if (do_dma) {
            const int nkoff = (d <= 6) ? ((d + 2) * IDIM + ib * 64)
                                       : ((d - 7) * IDIM + ib * 64 + 64);
            dmaB(nkoff, (d + 2) % 3);
        }

        // (E) single barrier: batch(t+1) (+UH at d==8) retired; batch(t+2)
        //     stays in flight; lgkmcnt(0) so Bs[cbuf] reads are done before
        //     any wave's next-window DMA can overwrite it
        if (do_sync) {
            if (waitN == 2) asm volatile("s_waitcnt vmcnt(2) lgkmcnt(0)" ::: "memory");
            else            asm volatile("s_waitcnt vmcnt(0) lgkmcnt(0)" ::: "memory");
            __builtin_amdgcn_s_barrier();
            asm volatile("" ::: "memory");
        }
    };

    // ---- main loop: ib 0..14, full pipeline -------------------------------
    for (int ib = 0; ib < 15; ++ib) {
#pragma unroll
        for (int d = 0; d < D1; ++d)
            window(ib, d, /*uh*/ (d == 8), /*dma*/ true, /*wait*/ 2, /*sync*/ true);
    }
    // ---- tail: ib == 15 ---------------------------------------------------
    {
#pragma unroll
        for (int d = 0; d < 7; ++d)
            window(15, d, false, true, 2, true);         // t=135..141 (issues up to batch 143)
        window(15, 7, false, false, 0, true);            // t=142: drain batch(143)
        window(15, 8, false, false, 0, false);           // t=143: last MFMAs, no sync
    }

    // epilogue: D row = quad*4 + reg, col = lane&15 (m89-verified layout)
#pragma unroll
    for (int i = 0; i < 4; ++i) {
        int row = bm * 128 + wm * 64 + i * 16 + q * 4;
#pragma unroll
        for (int j = 0; j < 2; ++j) {
            int col = bn * 64 + wn * 32 + j * 16 + m16;
            float* op = out + (size_t)row * ODIM + col;
#pragma unroll
            for (int r2 = 0; r2 < 4; ++r2)
                op[(size_t)r2 * ODIM] = acc[i][j][r2] * INV_BSCALE;
        }
    }
}

// ---------------------------------------------------------------------------
// naive fallback (only if workspace can't hold Bt + U + H0, 52.4 MB)
// ---------------------------------------------------------------------------
__global__ void naive_kernel(const float* __restrict__ x, const float* __restrict__ C,
                             float* __restrict__ out) {
    __shared__ float hb[IDIM * D1];
    int b = blockIdx.x;
    int tid = threadIdx.x;
    for (int i = tid; i < IDIM; i += 256) {
        float h[D1];
        hermite9(x[(size_t)b * IDIM + i], h);
#pragma unroll
        for (int d = 0; d < D1; ++d) hb[i * D1 + d] = h[d];
    }
    __syncthreads();
    for (int o = tid; o < ODIM; o += 256) {
        float acc = 0.f;
        for (int i = 0; i < IDIM; ++i) {
            const float* cp = C + ((size_t)i * ODIM + o) * D1;
            const float* hp = hb + i * D1;
#pragma unroll
            for (int d = 0; d < D1; ++d) acc += hp[d] * cp[d];
        }
        out[(size_t)b * ODIM + o] = acc;
    }
}

// ---------------------------------------------------------------------------
extern "C" void kernel_launch(void* const* d_in, const int* in_sizes, int n_in,
                              void* d_out, int out_size, void* d_ws, size_t ws_size,
                              hipStream_t stream) {
    const float* x      = (const float*)d_in[0];   // [8192][1024]
    const float* coeffs = (const float*)d_in[1];   // [1024][1024][9]
    float* out = (float*)d_out;                    // [8192][1024]

    const size_t bt_bytes = (size_t)ODIM * KDIM * sizeof(_Float16);   // 18.9 MB
    const size_t u_bytes  = (size_t)MDIM * IDIM * sizeof(_Float16);   // 16.8 MB

    if (ws_size >= bt_bytes + 2 * u_bytes) {
        _Float16* Bt = (_Float16*)d_ws;
        _Float16* Uv = (_Float16*)((char*)d_ws + bt_bytes);
        _Float16* H0 = (_Float16*)((char*)d_ws + bt_bytes + u_bytes);
        hipLaunchKernelGGL(prep_all, dim3(1024 + 4096), dim3(256), 0, stream,
                           coeffs, x, Bt, Uv, H0);
        hipLaunchKernelGGL(gemm_fused5, dim3(16, 64), dim3(256), 0, stream, Uv, H0, Bt, out);
    } else {
        hipLaunchKernelGGL(naive_kernel, dim3(MDIM), dim3(256), 0, stream, x, coeffs, out);
    }
}

// Round 7
// 273.252 us; speedup vs baseline: 1.3581x; 1.3581x over previous
//
#include <hip/hip_runtime.h>

// Problem constants
#define MDIM 8192
#define IDIM 1024
#define ODIM 1024
#define D1   9            // DEGREE+1
#define KDIM (IDIM * D1)  // 9216, k = d*1024 + i ordering

typedef _Float16 half8   __attribute__((ext_vector_type(8)));
typedef _Float16 half2v  __attribute__((ext_vector_type(2)));
typedef float    float4v __attribute__((ext_vector_type(4)));

#define BSCALE 256.0f     // pre-scale B into f16-normal range (exact pow2)
#define INV_BSCALE (1.0f / 256.0f)
#define USCALE 5.123105625617661f    // sqrt(17) + 1
#define H0C 0.7511255444649425f     // pi^-1/4
#define SQRT2 1.4142135623730951f   // h1 = sqrt2 * u * h0

// ---------------------------------------------------------------------------
// hermite9 (fp32) — naive fallback only.
// ---------------------------------------------------------------------------
__device__ __forceinline__ void hermite9(float xv, float h[D1]) {
    float ax = fabsf(xv);
    float t  = __expf(-2.0f * ax);
    float th = (1.0f - t) / (1.0f + t);
    th = copysignf(th, xv);
    float u = th * USCALE;
    float g = __expf(-0.5f * u * u);
    h[0] = H0C * g;
    h[1] = SQRT2 * H0C * u * g;
    const float c1[D1] = {0.f, 0.f, 1.0f, 0.8164965809277260f, 0.7071067811865476f,
                          0.6324555320336759f, 0.5773502691896258f, 0.5345224838248488f, 0.5f};
    const float c2[D1] = {0.f, 0.f, 0.7071067811865476f, 0.8164965809277260f, 0.8660254037844386f,
                          0.8944271909999159f, 0.9128709291752769f, 0.9258200997725514f, 0.9354143466934853f};
#pragma unroll
    for (int d = 2; d < D1; ++d) h[d] = c1[d] * u * h[d - 1] - c2[d] * h[d - 2];
}

// ---------------------------------------------------------------------------
// prep_all: fused prep_b (blocks 0..1023) + prep_u (blocks 1024..5119).
// ---------------------------------------------------------------------------
__global__ __launch_bounds__(256) void prep_all(const float* __restrict__ C,
                                                const float* __restrict__ x,
                                                _Float16* __restrict__ Bt,
                                                _Float16* __restrict__ U,
                                                _Float16* __restrict__ H0) {
    __shared__ float lds[288 * 33];
    const int t = threadIdx.x;
    if (blockIdx.x < 1024) {
        // ---- prep_b: LDS transpose, 32i x 32o tile, half8 stores ----------
        const int ti = blockIdx.x & 31;
        const int to = blockIdx.x >> 5;
        const float* base = C + (size_t)ti * 32 * 9216 + (size_t)to * 32 * 9;
#pragma unroll
        for (int j = 0; j < 36; ++j) {
            int f   = t + 256 * j;
            int row = f / 288;
            int col = f - row * 288;
            lds[col * 33 + row] = base[(size_t)row * 9216 + col];
        }
        __syncthreads();
        _Float16* bb = Bt + (size_t)to * 32 * KDIM + ti * 32;
#pragma unroll
        for (int j = 0; j < 5; ++j) {
            int s = t + 256 * j;
            if (s < 1152) {
                int i8  = s & 3;          // which half8 within the 32-i run
                int odp = s >> 2;         // 0..287 = o_local*9 + d
                int ol  = odp / 9;
                int d   = odp - ol * 9;
                half8 vv;
#pragma unroll
                for (int e = 0; e < 8; ++e)
                    vv[e] = (_Float16)(lds[odp * 33 + i8 * 8 + e] * BSCALE);
                *(half8*)(bb + (size_t)ol * KDIM + d * IDIM + i8 * 8) = vv;
            }
        }
    } else {
        // ---- prep_u: x -> u = USCALE*tanh(x), h0 = pi^-1/4 exp(-u^2/2) ----
        size_t tt = (size_t)(blockIdx.x - 1024) * 256 + t;
        const float4* xp = (const float4*)(x + tt * 8);
        float4 a0 = xp[0], a1 = xp[1];
        float xv[8] = {a0.x, a0.y, a0.z, a0.w, a1.x, a1.y, a1.z, a1.w};
        half8 uu, hh;
#pragma unroll
        for (int e = 0; e < 8; ++e) {
            float v  = xv[e];
            float t2 = __expf(-2.0f * fabsf(v));
            float th = (1.0f - t2) / (1.0f + t2);
            float u  = copysignf(th, v) * USCALE;
            float g  = __expf(-0.5f * u * u);
            uu[e] = (_Float16)u;
            hh[e] = (_Float16)(H0C * g);
        }
        *(half8*)(U  + tt * 8) = uu;
        *(half8*)(H0 + tt * 8) = hh;
    }
}

// ---------------------------------------------------------------------------
// gemm_fused6: fused4 geometry (proven 181 us) + in-wave MFMA/VALU interleave.
//   Per window, the Hermite recurrence for A-slot p = i*2+ko is placed
//   IMMEDIATELY after the 4 MFMAs that consume hB8[p] — the recurrence's
//   ~12 pk-f16 ops issue into the MFMA pipe's stall shadow (one MFMA
//   occupies the matrix pipe ~19.6 cyc; the in-order wave can issue VALU
//   meanwhile). Round-4 counters showed MFMA (38%) and VALU (35%) running
//   serially phase-aligned; this makes the overlap in-wave, no cross-wave
//   luck needed.
//   A-operand in registers; Bs triple-buffered 3x16KB, DMA 2 windows ahead,
//   steady s_waitcnt vmcnt(4) (never 0 in main loop); UH prefetch at d==8
//   into then-dead u8/hA8 regs. 128x128 tile, 4 waves 2x2, grid 8x64.
// ---------------------------------------------------------------------------
__global__ __launch_bounds__(256, 2) void gemm_fused6(
    const _Float16* __restrict__ U,    // [8192][1024] f16
    const _Float16* __restrict__ H0,   // [8192][1024] f16
    const _Float16* __restrict__ Bt,   // [ODIM][KDIM], pre-scaled by 256
    float* __restrict__ out)           // [8192][ODIM]
{
    const int tid = threadIdx.x;
    const int w = tid >> 6;
    const int l = tid & 63;
    const int bn = blockIdx.x;    // n-tile 0..7
    const int bm = blockIdx.y;    // m-tile 0..63

    __shared__ _Float16 Bs[3][128 * 64];     // 48 KB, triple buffer

    // Bs staging: lane l, rep rr loads 16B; stored kgrp = (l&7)^(l>>3)
    const int lrow8 = l >> 3;
    const int kgrp  = (l & 7) ^ lrow8;
    const _Float16* Bg = Bt + ((size_t)(bn * 128 + w * 8 + lrow8) * KDIM + kgrp * 8);

    // compute-side fragment indices
    const int q   = l >> 4;
    const int m16 = l & 15;
    const int s3  = m16 & 7;
    const int wm  = w >> 1, wn = w & 1;

    // per-lane A-state: rows bm*128 + wm*64 + i16*16 + m16 (i16=0..3),
    // i-groups g = q + 4*ko (ko=0..1): 8 half8 slots, p = i16*2 + ko
    const size_t ubase = ((size_t)(bm * 128 + wm * 64 + m16)) << 10;

    constexpr float c1a[D1] = {0.f, 0.f, 1.0f, 0.8164965809277260f, 0.7071067811865476f,
                               0.6324555320336759f, 0.5773502691896258f, 0.5345224838248488f, 0.5f};
    constexpr float c2a[D1] = {0.f, 0.f, 0.7071067811865476f, 0.8164965809277260f, 0.8660254037844386f,
                               0.8944271909999159f, 0.9128709291752769f, 0.9258200997725514f, 0.9354143466934853f};

    half8 u8[8], hA8[8], hB8[8];

    // load u and h0 for i-block ib into u8 / hA8 (hA8 <- h0)
    auto loadUH = [&](int ib) {
        const int ibo = ib * 64;
#pragma unroll
        for (int i16 = 0; i16 < 4; ++i16)
#pragma unroll
            for (int ko = 0; ko < 2; ++ko) {
                const size_t off = ubase + ((size_t)(i16 * 16) << 10) + ibo + (q + 4 * ko) * 8;
                u8 [i16 * 2 + ko] = *(const half8*)(U  + off);
                hA8[i16 * 2 + ko] = *(const half8*)(H0 + off);
            }
    };

    // DMA one 128x64 B-tile (k-offset nkoff) into Bs[nbuf]
    auto dmaB = [&](int nkoff, int nbuf) {
#pragma unroll
        for (int rr = 0; rr < 4; ++rr)
            __builtin_amdgcn_global_load_lds(
                (const __attribute__((address_space(1))) void*)(Bg + (size_t)(rr * 32) * KDIM + nkoff),
                (__attribute__((address_space(3))) void*)((char*)&Bs[nbuf][0] + (rr * 4 + w) * 1024),
                16, 0, 0);
    };

    float4v acc[4][4] = {};

    // ---- prologue ---------------------------------------------------------
    loadUH(0);                 // 16 loads (oldest in FIFO)
    dmaB(0, 0);                // batch(0)
    dmaB(IDIM, 1);             // batch(1)
    // retire UH + batch(0); batch(1) stays in flight
    asm volatile("s_waitcnt vmcnt(4)" ::: "memory");
    __builtin_amdgcn_s_barrier();
    asm volatile("" ::: "memory");

    // ---- one window (t = ib*9 + d); d is compile-time within unroll -------
    auto window = [&](int ib, int d, bool do_uh, bool do_dma, int waitN, bool do_sync) {
        const int cbuf = d % 3;

        // (A) i-block UH prefetch: u8/hA8 are dead at d==8 (af uses hB8 only,
        //     recurrence skipped) — loads land before the vmcnt wait below
        if (do_uh) loadUH(ib + 1);

        const _Float16 s2 = (_Float16)SQRT2;
        const _Float16 c1 = (_Float16)c1a[d + 1 <= 8 ? d + 1 : 8];
        const _Float16 c2 = (_Float16)c2a[d + 1 <= 8 ? d + 1 : 8];
        const half8 s2v = {s2, s2, s2, s2, s2, s2, s2, s2};
        const half8 c1v = {c1, c1, c1, c1, c1, c1, c1, c1};
        const half8 c2v = {c2, c2, c2, c2, c2, c2, c2, c2};

        // (B) MFMA groups with the recurrence interleaved per slot
        __builtin_amdgcn_s_setprio(1);
#pragma unroll
        for (int ko = 0; ko < 2; ++ko) {
            const int slot = (q + 4 * ko) ^ s3;
            half8 bf[4];
#pragma unroll
            for (int j = 0; j < 4; ++j)
                bf[j] = *(const half8*)&Bs[cbuf][(wn * 64 + j * 16 + m16) * 64 + slot * 8];
#pragma unroll
            for (int i = 0; i < 4; ++i) {
                const int p = i * 2 + ko;
                half8 af = (d == 0) ? hA8[p] : hB8[p];
#pragma unroll
                for (int j = 0; j < 4; ++j)
                    acc[i][j] = __builtin_amdgcn_mfma_f32_16x16x32_f16(af, bf[j], acc[i][j], 0, 0, 0);
                // recurrence for slot p — issues into the MFMA shadow;
                // af was read above, so the overwrite is safe
                if (d == 0) {
                    hB8[p] = s2v * u8[p] * hA8[p];          // h1; hA8 keeps h0
                } else if (d <= 7) {
                    half8 tt = u8[p] * hB8[p];
                    half8 ht = c1v * tt - c2v * hA8[p];
                    hA8[p] = hB8[p];
                    hB8[p] = ht;
                }
            }
        }
        __builtin_amdgcn_s_setprio(0);

        // (C) DMA batch(t+2) -> Bs[(t+2)%3]
        if (do_dma) {
            const int nkoff = (d <= 6) ? ((d + 2) * IDIM + ib * 64)
                                       : ((d - 7) * IDIM + ib * 64 + 64);
            dmaB(nkoff, (d + 2) % 3);
        }

        // (D) single barrier: batch(t+1) (+UH at d==8) retired; batch(t+2)
        //     stays in flight; lgkmcnt(0) so Bs[cbuf] reads are done before
        //     any wave's next-window DMA can overwrite it
        if (do_sync) {
            if (waitN == 4) asm volatile("s_waitcnt vmcnt(4) lgkmcnt(0)" ::: "memory");
            else            asm volatile("s_waitcnt vmcnt(0) lgkmcnt(0)" ::: "memory");
            __builtin_amdgcn_s_barrier();
            asm volatile("" ::: "memory");
        }
    };

    // ---- main loop: ib 0..14, full pipeline -------------------------------
    for (int ib = 0; ib < 15; ++ib) {
#pragma unroll
        for (int d = 0; d < D1; ++d)
            window(ib, d, /*uh*/ (d == 8), /*dma*/ true, /*wait*/ 4, /*sync*/ true);
    }
    // ---- tail: ib == 15 ---------------------------------------------------
    {
#pragma unroll
        for (int d = 0; d < 7; ++d)
            window(15, d, false, true, 4, true);         // t=135..141 (issues up to batch 143)
        window(15, 7, false, false, 0, true);            // t=142: drain batch(143)
        window(15, 8, false, false, 0, false);           // t=143: last MFMAs, no sync
    }

    // epilogue: D row = quad*4 + reg, col = lane&15 (m89-verified layout)
#pragma unroll
    for (int i = 0; i < 4; ++i) {
        int row = bm * 128 + wm * 64 + i * 16 + q * 4;
#pragma unroll
        for (int j = 0; j < 4; ++j) {
            int col = bn * 128 + wn * 64 + j * 16 + m16;
            float* op = out + (size_t)row * ODIM + col;
#pragma unroll
            for (int r2 = 0; r2 < 4; ++r2)
                op[(size_t)r2 * ODIM] = acc[i][j][r2] * INV_BSCALE;
        }
    }
}

// ---------------------------------------------------------------------------
// naive fallback (only if workspace can't hold Bt + U + H0, 52.4 MB)
// ---------------------------------------------------------------------------
__global__ void naive_kernel(const float* __restrict__ x, const float* __restrict__ C,
                             float* __restrict__ out) {
    __shared__ float hb[IDIM * D1];
    int b = blockIdx.x;
    int tid = threadIdx.x;
    for (int i = tid; i < IDIM; i += 256) {
        float h[D1];
        hermite9(x[(size_t)b * IDIM + i], h);
#pragma unroll
        for (int d = 0; d < D1; ++d) hb[i * D1 + d] = h[d];
    }
    __syncthreads();
    for (int o = tid; o < ODIM; o += 256) {
        float acc = 0.f;
        for (int i = 0; i < IDIM; ++i) {
            const float* cp = C + ((size_t)i * ODIM + o) * D1;
            const float* hp = hb + i * D1;
#pragma unroll
            for (int d = 0; d < D1; ++d) acc += hp[d] * cp[d];
        }
        out[(size_t)b * ODIM + o] = acc;
    }
}

// ---------------------------------------------------------------------------
extern "C" void kernel_launch(void* const* d_in, const int* in_sizes, int n_in,
                              void* d_out, int out_size, void* d_ws, size_t ws_size,
                              hipStream_t stream) {
    const float* x      = (const float*)d_in[0];   // [8192][1024]
    const float* coeffs = (const float*)d_in[1];   // [1024][1024][9]
    float* out = (float*)d_out;                    // [8192][1024]

    const size_t bt_bytes = (size_t)ODIM * KDIM * sizeof(_Float16);   // 18.9 MB
    const size_t u_bytes  = (size_t)MDIM * IDIM * sizeof(_Float16);   // 16.8 MB

    if (ws_size >= bt_bytes + 2 * u_bytes) {
        _Float16* Bt = (_Float16*)d_ws;
        _Float16* Uv = (_Float16*)((char*)d_ws + bt_bytes);
        _Float16* H0 = (_Float16*)((char*)d_ws + bt_bytes + u_bytes);
        hipLaunchKernelGGL(prep_all, dim3(1024 + 4096), dim3(256), 0, stream,
                           coeffs, x, Bt, Uv, H0);
        hipLaunchKernelGGL(gemm_fused6, dim3(8, 64), dim3(256), 0, stream, Uv, H0, Bt, out);
    } else {
        hipLaunchKernelGGL(naive_kernel, dim3(MDIM), dim3(256), 0, stream, x, coeffs, out);
    }
}